// Round 3
// baseline (600.511 us; speedup 1.0000x reference)
//
#include <hip/hip_runtime.h>
#include <math.h>

// Problem shape (fixed by reference setup_inputs)
#define BATCH 32
#define SEQ   4096
#define HID   768
#define HV4   (HID / 4)                       // 192 float4 per row
#define CHUNKS 32                             // chunks per batch -> 1024 blocks = 4/CU
#define ROWS_PER_BLOCK (SEQ / CHUNKS)         // 128
#define NWAVES 4
#define ROWS_PER_WAVE (ROWS_PER_BLOCK / NWAVES) // 32
#define RGROUP 4                              // rows processed together (ILP)

__device__ __forceinline__ float dot4(float4 a, float4 b) {
  return a.x * b.x + a.y * b.y + a.z * b.z + a.w * b.w;
}

// Single fused kernel: one block per (chunk, batch). Each wave runs online
// softmax over its 32 rows (read ONCE: dot + accumulate from registers).
// Block combines 4 wave partials in LDS, writes (m, l, O[768]) to ws, then
// the last-arriving block of each batch merges the 32 partials and writes out.
__global__ __launch_bounds__(256, 4)
void attn_fused(const float* __restrict__ hidden,
                const float* __restrict__ q,
                int* __restrict__ cnt,          // [BATCH], pre-zeroed
                float* __restrict__ m_ws,
                float* __restrict__ l_ws,
                float* __restrict__ o_ws,
                float* __restrict__ out) {
  const int chunk = blockIdx.x;
  const int b     = blockIdx.y;
  const int tid   = threadIdx.x;
  const int wave  = tid >> 6;
  const int lane  = tid & 63;

  // Query fragment for this lane: h = 4*lane..4*lane+3, +256, +512
  const float4* q4 = reinterpret_cast<const float4*>(q);
  const float4 qa = q4[lane];
  const float4 qb = q4[lane + 64];
  const float4 qc = q4[lane + 128];

  float m = -INFINITY;
  float l = 0.0f;
  float4 oa = make_float4(0.f, 0.f, 0.f, 0.f);
  float4 ob = make_float4(0.f, 0.f, 0.f, 0.f);
  float4 oc = make_float4(0.f, 0.f, 0.f, 0.f);

  const int row0 = chunk * ROWS_PER_BLOCK + wave * ROWS_PER_WAVE;
  const float4* base = reinterpret_cast<const float4*>(hidden)
                     + ((size_t)b * SEQ + (size_t)row0) * HV4;

  for (int g = 0; g < ROWS_PER_WAVE; g += RGROUP) {
    float4 ra[RGROUP], rb[RGROUP], rc[RGROUP];
    #pragma unroll
    for (int r = 0; r < RGROUP; ++r) {
      const float4* rp = base + (size_t)(g + r) * HV4;
      ra[r] = rp[lane];
      rb[r] = rp[lane + 64];
      rc[r] = rp[lane + 128];
    }

    float pd[RGROUP];
    #pragma unroll
    for (int r = 0; r < RGROUP; ++r)
      pd[r] = dot4(ra[r], qa) + dot4(rb[r], qb) + dot4(rc[r], qc);

    // 4 interleaved 64-lane butterfly sums -> scores wave-uniform afterwards
    #pragma unroll
    for (int off = 32; off >= 1; off >>= 1) {
      #pragma unroll
      for (int r = 0; r < RGROUP; ++r)
        pd[r] += __shfl_xor(pd[r], off, 64);
    }

    const float gm = fmaxf(fmaxf(pd[0], pd[1]), fmaxf(pd[2], pd[3]));
    if (gm > m) {                       // wave-uniform branch
      const float a = __expf(m - gm);   // exp(-inf)=0 on first group
      l *= a;
      oa.x *= a; oa.y *= a; oa.z *= a; oa.w *= a;
      ob.x *= a; ob.y *= a; ob.z *= a; ob.w *= a;
      oc.x *= a; oc.y *= a; oc.z *= a; oc.w *= a;
      m = gm;
    }

    float p[RGROUP];
    #pragma unroll
    for (int r = 0; r < RGROUP; ++r) {
      p[r] = __expf(pd[r] - m);
      l += p[r];
    }
    #pragma unroll
    for (int r = 0; r < RGROUP; ++r) {
      oa.x += p[r] * ra[r].x; oa.y += p[r] * ra[r].y;
      oa.z += p[r] * ra[r].z; oa.w += p[r] * ra[r].w;
      ob.x += p[r] * rb[r].x; ob.y += p[r] * rb[r].y;
      ob.z += p[r] * rb[r].z; ob.w += p[r] * rb[r].w;
      oc.x += p[r] * rc[r].x; oc.y += p[r] * rc[r].y;
      oc.z += p[r] * rc[r].z; oc.w += p[r] * rc[r].w;
    }
  }

  // Combine the 4 wave partials in LDS
  __shared__ float s_o[NWAVES][HID];   // 12 KB
  __shared__ float s_m[NWAVES];
  __shared__ float s_l[NWAVES];
  __shared__ int s_last;
  float4* so4 = reinterpret_cast<float4*>(s_o[wave]);
  so4[lane]       = oa;
  so4[lane + 64]  = ob;
  so4[lane + 128] = oc;
  if (lane == 0) { s_m[wave] = m; s_l[wave] = l; }
  __syncthreads();

  const float mb = fmaxf(fmaxf(s_m[0], s_m[1]), fmaxf(s_m[2], s_m[3]));
  const float a0 = __expf(s_m[0] - mb);
  const float a1 = __expf(s_m[1] - mb);
  const float a2 = __expf(s_m[2] - mb);
  const float a3 = __expf(s_m[3] - mb);
  const float lb = a0 * s_l[0] + a1 * s_l[1] + a2 * s_l[2] + a3 * s_l[3];

  const int pidx = b * CHUNKS + chunk;
  float* O = o_ws + (size_t)pidx * HID;
  #pragma unroll
  for (int j = 0; j < 3; ++j) {
    const int h = tid + 256 * j;
    O[h] = a0 * s_o[0][h] + a1 * s_o[1][h] + a2 * s_o[2][h] + a3 * s_o[3][h];
  }
  if (tid == 0) { m_ws[pidx] = mb; l_ws[pidx] = lb; }

  // --- last-block-per-batch merge ---
  __syncthreads();                     // all partial stores issued
  if (tid == 0) {
    __threadfence();                   // release: partials visible device-wide
    const int old = atomicAdd(&cnt[b], 1);
    s_last = (old == CHUNKS - 1);
  }
  __syncthreads();
  if (!s_last) return;

  __threadfence();                     // acquire: see all other blocks' partials

  float mg = -INFINITY;
  for (int c = 0; c < CHUNKS; ++c)
    mg = fmaxf(mg, m_ws[b * CHUNKS + c]);

  float L = 0.0f;
  float acc0 = 0.f, acc1 = 0.f, acc2 = 0.f;
  for (int c = 0; c < CHUNKS; ++c) {
    const int pi = b * CHUNKS + c;
    const float a = __expf(m_ws[pi] - mg);
    L += a * l_ws[pi];
    const float* Oc = o_ws + (size_t)pi * HID;
    acc0 += a * Oc[tid];
    acc1 += a * Oc[tid + 256];
    acc2 += a * Oc[tid + 512];
  }
  const float inv = 1.0f / L;
  out[(size_t)b * HID + tid]       = acc0 * inv;
  out[(size_t)b * HID + tid + 256] = acc1 * inv;
  out[(size_t)b * HID + tid + 512] = acc2 * inv;
}

extern "C" void kernel_launch(void* const* d_in, const int* in_sizes, int n_in,
                              void* d_out, int out_size, void* d_ws, size_t ws_size,
                              hipStream_t stream) {
  const float* hidden = (const float*)d_in[0];   // [32, 4096, 768] fp32
  const float* q      = (const float*)d_in[1];   // [1, 768] fp32
  float* out = (float*)d_out;                    // [32, 768] fp32

  // Workspace: cnt[32] (int) | m[1024] | l[1024] | O[1024*768]  (~3.2 MB)
  int*   cnt  = (int*)d_ws;
  float* m_ws = (float*)d_ws + 32;
  float* l_ws = m_ws + BATCH * CHUNKS;
  float* o_ws = l_ws + BATCH * CHUNKS;

  hipMemsetAsync(cnt, 0, BATCH * sizeof(int), stream);  // zero completion counters

  dim3 grid(CHUNKS, BATCH);
  attn_fused<<<grid, 256, 0, stream>>>(hidden, q, cnt, m_ws, l_ws, o_ws, out);
}

// Round 4
// 495.673 us; speedup vs baseline: 1.2115x; 1.2115x over previous
//
#include <hip/hip_runtime.h>
#include <math.h>

// Problem shape (fixed by reference setup_inputs)
#define BATCH 32
#define SEQ   4096
#define HID   768
#define HV4   (HID / 4)                       // 192 float4 per row
#define CHUNKS 64                             // chunks per batch
#define ROWS_PER_BLOCK (SEQ / CHUNKS)         // 64
#define NWAVES 4
#define ROWS_PER_WAVE (ROWS_PER_BLOCK / NWAVES) // 16
#define RGROUP 4                              // rows processed together (ILP)

// native clang vector type so __builtin_nontemporal_load works
typedef __attribute__((ext_vector_type(4))) float f4v;

__device__ __forceinline__ float dot4(f4v a, f4v b) {
  return a.x * b.x + a.y * b.y + a.z * b.z + a.w * b.w;
}

// Pass 1: one block per (chunk, batch). Each wave runs online softmax over its
// 16 rows in groups of 4. Rows are read ONCE (nontemporal: streaming data,
// never re-read — don't pollute L2/L3). Block combines 4 wave partials in LDS,
// writes (m, l, O[768]) per chunk.
__global__ __launch_bounds__(256, 4)
void attn_pass1(const float* __restrict__ hidden,
                const float* __restrict__ q,
                float* __restrict__ m_ws,
                float* __restrict__ l_ws,
                float* __restrict__ o_ws) {
  const int chunk = blockIdx.x;
  const int b     = blockIdx.y;
  const int tid   = threadIdx.x;
  const int wave  = tid >> 6;
  const int lane  = tid & 63;

  // Query fragment for this lane: h = 4*lane..4*lane+3, +256, +512
  const f4v* q4 = reinterpret_cast<const f4v*>(q);
  const f4v qa = q4[lane];
  const f4v qb = q4[lane + 64];
  const f4v qc = q4[lane + 128];

  float m = -INFINITY;
  float l = 0.0f;
  f4v oa = (f4v)0.0f;
  f4v ob = (f4v)0.0f;
  f4v oc = (f4v)0.0f;

  const int row0 = chunk * ROWS_PER_BLOCK + wave * ROWS_PER_WAVE;
  const f4v* base = reinterpret_cast<const f4v*>(hidden)
                  + ((size_t)b * SEQ + (size_t)row0) * HV4;

  for (int g = 0; g < ROWS_PER_WAVE; g += RGROUP) {
    f4v ra[RGROUP], rb[RGROUP], rc[RGROUP];
    #pragma unroll
    for (int r = 0; r < RGROUP; ++r) {
      const f4v* rp = base + (size_t)(g + r) * HV4;
      ra[r] = __builtin_nontemporal_load(rp + lane);
      rb[r] = __builtin_nontemporal_load(rp + lane + 64);
      rc[r] = __builtin_nontemporal_load(rp + lane + 128);
    }

    float pd[RGROUP];
    #pragma unroll
    for (int r = 0; r < RGROUP; ++r)
      pd[r] = dot4(ra[r], qa) + dot4(rb[r], qb) + dot4(rc[r], qc);

    // 4 interleaved 64-lane butterfly sums -> scores wave-uniform afterwards
    #pragma unroll
    for (int off = 32; off >= 1; off >>= 1) {
      #pragma unroll
      for (int r = 0; r < RGROUP; ++r)
        pd[r] += __shfl_xor(pd[r], off, 64);
    }

    const float gm = fmaxf(fmaxf(pd[0], pd[1]), fmaxf(pd[2], pd[3]));
    if (gm > m) {                       // wave-uniform branch
      const float a = __expf(m - gm);   // exp(-inf)=0 on first group
      l *= a;
      oa *= a; ob *= a; oc *= a;
      m = gm;
    }

    #pragma unroll
    for (int r = 0; r < RGROUP; ++r) {
      const float p = __expf(pd[r] - m);
      l += p;
      oa += p * ra[r];
      ob += p * rb[r];
      oc += p * rc[r];
    }
  }

  // Combine the 4 wave partials in LDS
  __shared__ float s_o[NWAVES][HID];   // 12 KB
  __shared__ float s_m[NWAVES];
  __shared__ float s_l[NWAVES];
  f4v* so4 = reinterpret_cast<f4v*>(s_o[wave]);
  so4[lane]       = oa;
  so4[lane + 64]  = ob;
  so4[lane + 128] = oc;
  if (lane == 0) { s_m[wave] = m; s_l[wave] = l; }
  __syncthreads();

  const float mb = fmaxf(fmaxf(s_m[0], s_m[1]), fmaxf(s_m[2], s_m[3]));
  const float a0 = __expf(s_m[0] - mb);
  const float a1 = __expf(s_m[1] - mb);
  const float a2 = __expf(s_m[2] - mb);
  const float a3 = __expf(s_m[3] - mb);
  const float lb = a0 * s_l[0] + a1 * s_l[1] + a2 * s_l[2] + a3 * s_l[3];

  const int pidx = b * CHUNKS + chunk;
  float* O = o_ws + (size_t)pidx * HID;
  #pragma unroll
  for (int j = 0; j < 3; ++j) {
    const int h = tid + 256 * j;
    O[h] = a0 * s_o[0][h] + a1 * s_o[1][h] + a2 * s_o[2][h] + a3 * s_o[3][h];
  }
  if (tid == 0) { m_ws[pidx] = mb; l_ws[pidx] = lb; }
}

// Pass 2: one thread per output element. grid (BATCH, 6) x 128 threads.
// m/l loads are redundant per thread but fully L2-resident (8 KB total).
__global__ __launch_bounds__(128)
void attn_pass2(const float* __restrict__ m_ws,
                const float* __restrict__ l_ws,
                const float* __restrict__ o_ws,
                float* __restrict__ out) {
  const int b = blockIdx.x;
  const int h = blockIdx.y * 128 + threadIdx.x;

  float mg = -INFINITY;
  #pragma unroll 8
  for (int c = 0; c < CHUNKS; ++c)
    mg = fmaxf(mg, m_ws[b * CHUNKS + c]);

  float L = 0.0f;
  float acc = 0.0f;
  #pragma unroll 8
  for (int c = 0; c < CHUNKS; ++c) {
    const int pi = b * CHUNKS + c;
    const float a = __expf(m_ws[pi] - mg);
    L += a * l_ws[pi];
    acc += a * o_ws[(size_t)pi * HID + h];
  }
  out[(size_t)b * HID + h] = acc / L;
}

extern "C" void kernel_launch(void* const* d_in, const int* in_sizes, int n_in,
                              void* d_out, int out_size, void* d_ws, size_t ws_size,
                              hipStream_t stream) {
  const float* hidden = (const float*)d_in[0];   // [32, 4096, 768] fp32
  const float* q      = (const float*)d_in[1];   // [1, 768] fp32
  float* out = (float*)d_out;                    // [32, 768] fp32

  // Workspace layout: m[2048] | l[2048] | O[2048*768]  (~6.3 MB total)
  float* m_ws = (float*)d_ws;
  float* l_ws = m_ws + BATCH * CHUNKS;
  float* o_ws = l_ws + BATCH * CHUNKS;

  dim3 grid1(CHUNKS, BATCH);
  attn_pass1<<<grid1, 256, 0, stream>>>(hidden, q, m_ws, l_ws, o_ws);
  dim3 grid2(BATCH, HID / 128);
  attn_pass2<<<grid2, 128, 0, stream>>>(m_ws, l_ws, o_ws, out);
}